// Round 6
// baseline (379.049 us; speedup 1.0000x reference)
//
#include <hip/hip_runtime.h>
#include <hip/hip_bf16.h>
#include <stdint.h>

#define IC 32
#define OC 32
#define NREG 33      // 32 hinges -> 33 piecewise-linear regions

typedef __attribute__((ext_vector_type(8))) short short8;
typedef __attribute__((ext_vector_type(4))) float f32x4;

static __device__ __forceinline__ short f2bf(float f) {
    __bf16 b = (__bf16)f;
    return __builtin_bit_cast(short, b);
}
static __device__ __forceinline__ float bf2f(short s) {
    return (float)__builtin_bit_cast(__bf16, s);
}

// ===========================================================================
// Piecewise-linear setup (validated R2..R5):
//   edge:  W_r(t)=P_r + t*Q_r (32x32)  |  angle: f_r(t)=c_r + t*d_r (32)
// ===========================================================================
__global__ void setup_sort(const float* __restrict__ eW1, const float* __restrict__ eb1,
                           const float* __restrict__ aW1, const float* __restrict__ ab1,
                           float* __restrict__ ehs, float* __restrict__ ahs,
                           unsigned* __restrict__ emask, unsigned* __restrict__ amask)
{
    __shared__ float hv[64];
    __shared__ float sv[64];
    __shared__ int   sk[64];
    int tid = threadIdx.x;
    {
        int k = tid & 31;
        float w = (tid < 32) ? eW1[k] : aW1[k];
        float b = (tid < 32) ? eb1[k] : ab1[k];
        hv[tid] = (w != 0.f) ? (-b / w) : 1e30f;
    }
    __syncthreads();
    {
        int grp = tid >> 5, k = tid & 31;
        float v = hv[tid];
        int rank = 0;
        for (int j = 0; j < 32; ++j) {
            float u = hv[grp * 32 + j];
            rank += (u < v) || (u == v && j < k);
        }
        sv[grp * 32 + rank] = v;
        sk[grp * 32 + rank] = k;
    }
    __syncthreads();
    if (tid < 32) ehs[tid] = sv[tid];
    else          ahs[tid - 32] = sv[tid];
    if (tid == 0) {
        unsigned m = 0;
        for (int k = 0; k < 32; ++k) {
            float w = eW1[k], b = eb1[k];
            if (w < 0.f || (w == 0.f && b > 0.f)) m |= 1u << k;
        }
        emask[0] = m;
        for (int r = 1; r <= 32; ++r) {
            int k = sk[r - 1];
            float w = eW1[k];
            if (w > 0.f) m |= 1u << k; else if (w < 0.f) m &= ~(1u << k);
            emask[r] = m;
        }
    } else if (tid == 1) {
        unsigned m = 0;
        for (int k = 0; k < 32; ++k) {
            float w = aW1[k], b = ab1[k];
            if (w < 0.f || (w == 0.f && b > 0.f)) m |= 1u << k;
        }
        amask[0] = m;
        for (int r = 1; r <= 32; ++r) {
            int k = sk[32 + r - 1];
            float w = aW1[k];
            if (w > 0.f) m |= 1u << k; else if (w < 0.f) m &= ~(1u << k);
            amask[r] = m;
        }
    }
}

// ePQ (bf16): [r][o][kk], kk<32 -> P_r[kk,o], kk>=32 -> Q_r[kk-32,o]
// aCD (f32):  [r][0..31]=c_r, [r][32..63]=d_r
__global__ __launch_bounds__(256) void setup_tables(
    const float* __restrict__ eW1, const float* __restrict__ eb1,
    const float* __restrict__ eW2, const float* __restrict__ eb2,
    const float* __restrict__ aW1, const float* __restrict__ ab1,
    const float* __restrict__ aW2, const float* __restrict__ ab2,
    const unsigned* __restrict__ emask, const unsigned* __restrict__ amask,
    __hip_bfloat16* __restrict__ ePQ, float* __restrict__ aCD)
{
    int b = blockIdx.x, tid = threadIdx.x;
    if (b < NREG) {
        unsigned m = emask[b];
        for (int pos = tid; pos < 1024; pos += 256) {   // pos = i*32+o
            int i = pos >> 5, o = pos & 31;
            float P = eb2[pos];
            float Q = 0.f;
            for (int k = 0; k < 32; ++k) {
                if (m & (1u << k)) {
                    float w2 = eW2[k * 1024 + pos];
                    P += eb1[k] * w2;
                    Q += eW1[k] * w2;
                }
            }
            ePQ[b * 2048 + o * 64 + i]      = (__hip_bfloat16)P;
            ePQ[b * 2048 + o * 64 + 32 + i] = (__hip_bfloat16)Q;
        }
    } else if (tid < 32) {
        int r = b - NREG, o = tid;
        unsigned m = amask[r];
        float c = ab2[o], d = 0.f;
        for (int k = 0; k < 32; ++k) {
            if (m & (1u << k)) {
                float w2 = aW2[k * 32 + o];
                c += ab1[k] * w2;
                d += aW1[k] * w2;
            }
        }
        aCD[r * 64 + o]      = c;
        aCD[r * 64 + 32 + o] = d;
    }
}

__global__ __launch_bounds__(256) void x_to_bf16(const float* __restrict__ x,
                                                 __hip_bfloat16* __restrict__ xbf, int n)
{
    int i = (blockIdx.x * 256 + threadIdx.x) * 4;
    if (i + 3 < n) {
        float4 v = *(const float4*)(x + i);
        xbf[i]     = (__hip_bfloat16)v.x;
        xbf[i + 1] = (__hip_bfloat16)v.y;
        xbf[i + 2] = (__hip_bfloat16)v.z;
        xbf[i + 3] = (__hip_bfloat16)v.w;
    } else {
        for (int k = i; k < n; ++k) xbf[k] = (__hip_bfloat16)x[k];
    }
}

// ===========================================================================
// hist: edge blocks -> region bins (LDS) + edge dst-degree (global);
//       angle blocks -> angle node-degree (global).
// ===========================================================================
__global__ __launch_bounds__(512) void hist2(
    const int* __restrict__ edge_index, const float* __restrict__ edge_attr,
    const int* __restrict__ angle_index, const float* __restrict__ ehs,
    int* __restrict__ ebins, int* __restrict__ edeg, int* __restrict__ adeg,
    int E, int A, int EBLK)
{
    int tid = threadIdx.x, b = blockIdx.x;
    if (b < EBLK) {
        __shared__ int lh[NREG];
        __shared__ float she[32];
        if (tid < 32) she[tid] = ehs[tid];
        if (tid < NREG) lh[tid] = 0;
        __syncthreads();
        int e = b * 512 + tid;
        if (e < E) {
            float t = edge_attr[e];
            int r = 0;
#pragma unroll
            for (int j = 0; j < 32; ++j) r += (t > she[j]) ? 1 : 0;
            atomicAdd(&lh[r], 1);
            atomicAdd(&edeg[edge_index[e]], 1);
        }
        __syncthreads();
        if (tid < NREG && lh[tid]) atomicAdd(&ebins[tid], lh[tid]);
    } else {
        int a = (b - EBLK) * 512 + tid;
        if (a < A) atomicAdd(&adeg[angle_index[A + a]], 1);
    }
}

// ===========================================================================
// One-block scan: region starts (16-aligned) + exclusive scans of the two
// 50k node-degree arrays (chunked serial + Hillis-Steele over 1024 partials).
// ===========================================================================
__global__ __launch_bounds__(1024) void scan_all(
    const int* __restrict__ ebins, int* __restrict__ estarts,
    const int* __restrict__ edeg, int* __restrict__ estartsN,
    const int* __restrict__ adeg, int* __restrict__ astartsN, int NN)
{
    __shared__ int part[1024];
    int tid = threadIdx.x;
    if (tid == 0) {
        int s = 0;
        for (int r = 0; r < NREG; ++r) { estarts[r] = s; s += (ebins[r] + 15) & ~15; }
        estarts[NREG] = s;
    }
    const int CH = (NN + 1023) / 1024;
    const int lo = tid * CH, hi = min(lo + CH, NN);
    // phase 1: edeg -> estartsN
    {
        int s = 0;
        for (int i = lo; i < hi; ++i) s += edeg[i];
        part[tid] = s;
        __syncthreads();
        for (int off = 1; off < 1024; off <<= 1) {
            int v = (tid >= off) ? part[tid - off] : 0;
            __syncthreads();
            part[tid] += v;
            __syncthreads();
        }
        int run = part[tid] - s;
        for (int i = lo; i < hi; ++i) { estartsN[i] = run; run += edeg[i]; }
        if (tid == 1023) estartsN[NN] = part[1023];
    }
    __syncthreads();
    // phase 2: adeg -> astartsN
    {
        int s = 0;
        for (int i = lo; i < hi; ++i) s += adeg[i];
        part[tid] = s;
        __syncthreads();
        for (int off = 1; off < 1024; off <<= 1) {
            int v = (tid >= off) ? part[tid - off] : 0;
            __syncthreads();
            part[tid] += v;
            __syncthreads();
        }
        int run = part[tid] - s;
        for (int i = lo; i < hi; ++i) { astartsN[i] = run; run += adeg[i]; }
        if (tid == 1023) astartsN[NN] = part[1023];
    }
}

// ===========================================================================
// scatter: edges -> (region-sorted payload se_t/se_src) + dst-sorted slot
// permutation nidx; angles -> node-sorted (sa_t, sa_r).
// ===========================================================================
__global__ __launch_bounds__(512) void scatter2(
    const int* __restrict__ edge_index, const float* __restrict__ edge_attr,
    const int* __restrict__ angle_index, const float* __restrict__ angles,
    const float* __restrict__ ehs, const float* __restrict__ ahs,
    const int* __restrict__ estarts, int* __restrict__ ecur,
    const int* __restrict__ estartsN, int* __restrict__ ecur50,
    const int* __restrict__ astartsN, int* __restrict__ acur50,
    float* __restrict__ se_t, int* __restrict__ se_src, int* __restrict__ nidx,
    float* __restrict__ sa_t, int* __restrict__ sa_r,
    int E, int A, int EBLK)
{
    int tid = threadIdx.x, b = blockIdx.x;
    if (b < EBLK) {
        __shared__ int lh[NREG], lb[NREG];
        __shared__ float sh[32];
        if (tid < 32) sh[tid] = ehs[tid];
        if (tid < NREG) lh[tid] = 0;
        __syncthreads();
        int e = b * 512 + tid;
        bool v = (e < E);
        int r = 0, myo = 0; float t = 0.f;
        if (v) {
            t = edge_attr[e];
#pragma unroll
            for (int j = 0; j < 32; ++j) r += (t > sh[j]) ? 1 : 0;
            myo = atomicAdd(&lh[r], 1);
        }
        __syncthreads();
        if (tid < NREG) lb[tid] = lh[tid] ? atomicAdd(&ecur[tid], lh[tid]) : 0;
        __syncthreads();
        if (v) {
            int regpos = estarts[r] + lb[r] + myo;
            se_t[regpos]   = t;
            se_src[regpos] = edge_index[E + e];
            int dst = edge_index[e];
            int npos = estartsN[dst] + atomicAdd(&ecur50[dst], 1);
            nidx[npos] = regpos;
        }
    } else {
        __shared__ float sha[32];
        if (tid < 32) sha[tid] = ahs[tid];
        __syncthreads();
        int a = (b - EBLK) * 512 + tid;
        if (a < A) {
            float t = angles[a];
            int r = 0;
#pragma unroll
            for (int j = 0; j < 32; ++j) r += (t > sha[j]) ? 1 : 0;
            int j = angle_index[A + a];
            int npos = astartsN[j] + atomicAdd(&acur50[j], 1);
            sa_t[npos] = t;
            sa_r[npos] = r;
        }
    }
}

__global__ __launch_bounds__(256) void tilereg_kernel(
    const int* __restrict__ ebins, const int* __restrict__ estarts,
    int* __restrict__ tileReg, int Tmax)
{
    int tau = blockIdx.x * 256 + threadIdx.x;
    if (tau >= Tmax) return;
    int s = tau * 16, reg = -1;
    for (int r = 0; r < NREG; ++r)
        if (s >= estarts[r] && s < estarts[r] + ebins[r]) reg = r;
    tileReg[tau] = reg;
}

// ===========================================================================
// Edge GEMM: wave = 16 edges x 32 outputs, K=64 (x | t*x) vs (P_r ; Q_r).
// C-tiles stored CONTIGUOUSLY to mbuf in region-sort slot order (plain,
// coalesced stores — zero atomics). Padding slots write garbage rows that
// are never referenced by nidx.
// ===========================================================================
__global__ __launch_bounds__(256) void edge_gemm2(
    const __hip_bfloat16* __restrict__ xbf,
    const float* __restrict__ se_t, const int* __restrict__ se_src,
    const int* __restrict__ tileReg, const __hip_bfloat16* __restrict__ ePQ,
    float* __restrict__ mbuf, int Tmax, int NN)
{
    int tid = threadIdx.x, lane = tid & 63;
    int tau = blockIdx.x * 4 + (tid >> 6);
    if (tau >= Tmax) return;
    int r = tileReg[tau];
    if (r < 0) return;

    int q = lane >> 4, l15 = lane & 15, kb = q * 8;
    const short* Tb = (const short*)ePQ + r * 2048;
    short8 B00 = *(const short8*)(Tb + l15 * 64 + kb);
    short8 B10 = *(const short8*)(Tb + l15 * 64 + 32 + kb);
    short8 B01 = *(const short8*)(Tb + (16 + l15) * 64 + kb);
    short8 B11 = *(const short8*)(Tb + (16 + l15) * 64 + 32 + kb);

    int s = tau * 16 + l15;
    int src = se_src[s];
    float t = se_t[s];
    if ((unsigned)src >= (unsigned)NN) { src = 0; t = 0.f; }   // padding slot
    short8 a0 = *(const short8*)((const short*)xbf + src * IC + kb);
    short8 a1;
#pragma unroll
    for (int j = 0; j < 8; ++j) a1[j] = f2bf(t * bf2f(a0[j]));

    f32x4 z = {0.f, 0.f, 0.f, 0.f};
    f32x4 acc0 = __builtin_amdgcn_mfma_f32_16x16x32_bf16(a0, B00, z, 0, 0, 0);
    acc0 = __builtin_amdgcn_mfma_f32_16x16x32_bf16(a1, B10, acc0, 0, 0, 0);
    f32x4 acc1 = __builtin_amdgcn_mfma_f32_16x16x32_bf16(a0, B01, z, 0, 0, 0);
    acc1 = __builtin_amdgcn_mfma_f32_16x16x32_bf16(a1, B11, acc1, 0, 0, 0);

    // C row (q*4+rr) = slot tau*16+q*4+rr; cols l15 and 16+l15
#pragma unroll
    for (int rr = 0; rr < 4; ++rr) {
        size_t row = (size_t)(tau * 16 + q * 4 + rr) * OC;
        mbuf[row + l15]      = acc0[rr];
        mbuf[row + 16 + l15] = acc1[rr];
    }
}

// ===========================================================================
// Reduce: thread (n,o). Edge part: sum mbuf rows via nidx (coalesced 128B
// row gathers). Angle part: segment of (t,r) -> c_r[o]+t*d_r[o] from LDS
// table. Writes out exactly once -> no zeroing, no atomics.
// ===========================================================================
__global__ __launch_bounds__(256) void reduce_k(
    const float* __restrict__ mbuf, const int* __restrict__ nidx,
    const int* __restrict__ estartsN,
    const float* __restrict__ sa_t, const int* __restrict__ sa_r,
    const int* __restrict__ astartsN,
    const float* __restrict__ aCD, float* __restrict__ out, int NN)
{
    __shared__ float scd[NREG * 64];
    int tid = threadIdx.x;
    for (int i = tid; i < NREG * 64; i += 256) scd[i] = aCD[i];
    __syncthreads();
    int n = blockIdx.x * 8 + (tid >> 5);
    if (n >= NN) return;
    int o = tid & 31;
    float acc = 0.f;
    int e0 = estartsN[n], e1 = estartsN[n + 1];
    for (int p = e0; p < e1; ++p) {
        int slot = nidx[p];
        acc += mbuf[(size_t)slot * OC + o];
    }
    int a0 = astartsN[n], a1 = astartsN[n + 1];
    for (int p = a0; p < a1; ++p) {
        float t = sa_t[p];
        int r = sa_r[p];
        acc += scd[r * 64 + o] + t * scd[r * 64 + 32 + o];
    }
    out[n * OC + o] = acc;
}

// ===========================================================================
// Fallback (round-1, known-good 194us)
// ===========================================================================
__global__ void zero_kernel(float* __restrict__ out, int n) {
    int i = (blockIdx.x * blockDim.x + threadIdx.x) * 4;
    if (i + 3 < n) *(float4*)(out + i) = make_float4(0.f, 0.f, 0.f, 0.f);
    else for (int k = i; k < n; ++k) out[k] = 0.f;
}

__global__ __launch_bounds__(256) void edge_kernel_fb(
    const float* __restrict__ x, const int* __restrict__ edge_index,
    const float* __restrict__ edge_attr,
    const float* __restrict__ eW1, const float* __restrict__ eb1,
    const float* __restrict__ eW2, const float* __restrict__ eb2,
    float* __restrict__ out, int E)
{
    const int tid = threadIdx.x, lane = tid & 63;
    const int gwave = blockIdx.x * 4 + (tid >> 6);
    const int ot = gwave & 1, tile0 = gwave >> 1;
    const int tstride = (gridDim.x * 4) >> 1;
    const int q = lane >> 4, l15 = lane & 15, ocol = ot * 16 + l15;
    short8 Bf[33];
#pragma unroll
    for (int s = 0; s < 32; ++s) {
        short8 bb;
#pragma unroll
        for (int j = 0; j < 8; ++j) bb[j] = f2bf(eW2[s * 1024 + (q * 8 + j) * 32 + ocol]);
        Bf[s] = bb;
    }
    {
        short8 bb;
#pragma unroll
        for (int j = 0; j < 8; ++j) bb[j] = f2bf(eb2[(q * 8 + j) * 32 + ocol]);
        Bf[32] = bb;
    }
    const int numTiles = (E + 15) >> 4;
    for (int tile = tile0; tile < numTiles; tile += tstride) {
        const int e16 = tile << 4, eA = e16 + l15;
        const bool va = (eA < E);
        const int eAc = va ? eA : 0;
        const float t = va ? edge_attr[eAc] : 0.f;
        const int col = va ? edge_index[E + eAc] : 0;
        const float* xp = x + col * IC + q * 8;
        const float4 xlo = *(const float4*)(xp);
        const float4 xhi = *(const float4*)(xp + 4);
        float xf[8] = {xlo.x, xlo.y, xlo.z, xlo.w, xhi.x, xhi.y, xhi.z, xhi.w};
        f32x4 acc = {0.f, 0.f, 0.f, 0.f};
#pragma unroll
        for (int s = 0; s < 32; ++s) {
            float hs = t * eW1[s] + eb1[s];
            hs = hs > 0.f ? hs : 0.f;
            short8 a;
#pragma unroll
            for (int j = 0; j < 8; ++j) a[j] = f2bf(xf[j] * hs);
            acc = __builtin_amdgcn_mfma_f32_16x16x32_bf16(a, Bf[s], acc, 0, 0, 0);
        }
        {
            short8 a;
#pragma unroll
            for (int j = 0; j < 8; ++j) a[j] = f2bf(xf[j]);
            acc = __builtin_amdgcn_mfma_f32_16x16x32_bf16(a, Bf[32], acc, 0, 0, 0);
        }
        const int ebase = e16 + q * 4;
#pragma unroll
        for (int r = 0; r < 4; ++r) {
            const int er = ebase + r;
            if (er < E) unsafeAtomicAdd(out + edge_index[er] * OC + ocol, acc[r]);
        }
    }
}

__global__ __launch_bounds__(256) void angle_kernel_fb(
    const float* __restrict__ angles, const int* __restrict__ angle_index,
    const float* __restrict__ aW1, const float* __restrict__ ab1,
    const float* __restrict__ aW2, const float* __restrict__ ab2,
    float* __restrict__ out, int A)
{
    const int tid = threadIdx.x, lane = tid & 63;
    const int gwave = blockIdx.x * 4 + (tid >> 6);
    const int ot = gwave & 1, tile0 = gwave >> 1;
    const int tstride = (gridDim.x * 4) >> 1;
    const int q = lane >> 4, l15 = lane & 15, ocol = ot * 16 + l15;
    short8 Bf;
#pragma unroll
    for (int j = 0; j < 8; ++j) Bf[j] = f2bf(aW2[(q * 8 + j) * 32 + ocol]);
    const float bias = ab2[ocol];
    float w1[8], b1[8];
#pragma unroll
    for (int j = 0; j < 8; ++j) { w1[j] = aW1[q * 8 + j]; b1[j] = ab1[q * 8 + j]; }
    const int numTiles = (A + 15) >> 4;
    for (int tile = tile0; tile < numTiles; tile += tstride) {
        const int a16 = tile << 4, ai = a16 + l15;
        const float t = (ai < A) ? angles[ai] : 0.f;
        short8 a;
#pragma unroll
        for (int j = 0; j < 8; ++j) {
            float h = t * w1[j] + b1[j];
            h = h > 0.f ? h : 0.f;
            a[j] = f2bf(h);
        }
        f32x4 acc = {0.f, 0.f, 0.f, 0.f};
        acc = __builtin_amdgcn_mfma_f32_16x16x32_bf16(a, Bf, acc, 0, 0, 0);
        const int abase = a16 + q * 4;
#pragma unroll
        for (int r = 0; r < 4; ++r) {
            const int ar = abase + r;
            if (ar < A) unsafeAtomicAdd(out + angle_index[A + ar] * OC + ocol, acc[r] + bias);
        }
    }
}

// ===========================================================================
extern "C" void kernel_launch(void* const* d_in, const int* in_sizes, int n_in,
                              void* d_out, int out_size, void* d_ws, size_t ws_size,
                              hipStream_t stream)
{
    const float* x          = (const float*)d_in[0];
    const int*   edge_index = (const int*)d_in[1];
    const float* edge_attr  = (const float*)d_in[2];
    const int*   angle_index= (const int*)d_in[3];
    const float* angles     = (const float*)d_in[4];
    const float* eW1        = (const float*)d_in[5];
    const float* eb1        = (const float*)d_in[6];
    const float* eW2        = (const float*)d_in[7];
    const float* eb2        = (const float*)d_in[8];
    const float* aW1        = (const float*)d_in[9];
    const float* ab1        = (const float*)d_in[10];
    const float* aW2        = (const float*)d_in[11];
    const float* ab2        = (const float*)d_in[12];
    float* out = (float*)d_out;

    const int E = in_sizes[1] / 2;
    const int A = in_sizes[3] / 3;
    const int NN = out_size / OC;                 // node count
    const int Smax = E + 16 * NREG;               // sorted edge slots
    const int Tmax = (E + 15) / 16 + NREG + 1;
    const int EBLK = (E + 511) / 512, ABLK = (A + 511) / 512;

    size_t off = 0;
    auto carve = [&](size_t bytes) {
        size_t o = off;
        off += (bytes + 255) & ~(size_t)255;
        return o;
    };
    char* wsb = (char*)d_ws;
    size_t o_ePQ   = carve((size_t)NREG * 2048 * 2);
    size_t o_aCD   = carve((size_t)NREG * 64 * 4);
    size_t o_ehs   = carve(128);
    size_t o_ahs   = carve(128);
    size_t o_emask = carve(NREG * 4);
    size_t o_amask = carve(NREG * 4);
    // zero block: meta(128 ints) | edeg(NN) | ecur50(NN) | adeg(NN) | acur50(NN)
    const size_t ZI = 128 + 4 * (size_t)NN;
    size_t o_zero  = carve(ZI * 4);
    size_t o_estN  = carve((size_t)(NN + 1) * 4);
    size_t o_astN  = carve((size_t)(NN + 1) * 4);
    size_t o_xbf   = carve((size_t)NN * IC * 2);
    size_t o_treg  = carve((size_t)Tmax * 4);
    size_t o_set   = carve((size_t)Smax * 4);
    size_t o_ses   = carve((size_t)Smax * 4);
    size_t o_nidx  = carve((size_t)E * 4);
    size_t o_sat   = carve((size_t)A * 4);
    size_t o_sar   = carve((size_t)A * 4);
    size_t o_mbuf  = carve(((size_t)Smax + 16) * OC * 4);
    size_t needed = off;

    if (needed <= ws_size) {
        __hip_bfloat16* ePQ = (__hip_bfloat16*)(wsb + o_ePQ);
        float* aCD   = (float*)(wsb + o_aCD);
        float* ehs   = (float*)(wsb + o_ehs);
        float* ahs   = (float*)(wsb + o_ahs);
        unsigned* emask = (unsigned*)(wsb + o_emask);
        unsigned* amask = (unsigned*)(wsb + o_amask);
        int* zb      = (int*)(wsb + o_zero);
        int* ebins   = zb;            // 33
        int* ecur    = zb + 40;       // 33
        int* estarts = zb + 80;       // 34 (written by scan, zeroing harmless)
        int* edeg    = zb + 128;
        int* ecur50  = edeg + NN;
        int* adeg    = ecur50 + NN;
        int* acur50  = adeg + NN;
        int* estartsN = (int*)(wsb + o_estN);
        int* astartsN = (int*)(wsb + o_astN);
        __hip_bfloat16* xbf = (__hip_bfloat16*)(wsb + o_xbf);
        int*   tileReg = (int*)(wsb + o_treg);
        float* se_t  = (float*)(wsb + o_set);
        int*   se_src= (int*)(wsb + o_ses);
        int*   nidx  = (int*)(wsb + o_nidx);
        float* sa_t  = (float*)(wsb + o_sat);
        int*   sa_r  = (int*)(wsb + o_sar);
        float* mbuf  = (float*)(wsb + o_mbuf);

        hipMemsetAsync(zb, 0, ZI * 4, stream);
        hipMemsetAsync(se_src, 0xFF, (size_t)Smax * 4, stream);  // padding: huge -> clamp

        setup_sort<<<1, 64, 0, stream>>>(eW1, eb1, aW1, ab1, ehs, ahs, emask, amask);
        setup_tables<<<2 * NREG, 256, 0, stream>>>(eW1, eb1, eW2, eb2,
                                                   aW1, ab1, aW2, ab2,
                                                   emask, amask, ePQ, aCD);
        x_to_bf16<<<(NN * IC / 4 + 255) / 256, 256, 0, stream>>>(x, xbf, NN * IC);
        hist2<<<EBLK + ABLK, 512, 0, stream>>>(edge_index, edge_attr, angle_index,
                                               ehs, ebins, edeg, adeg, E, A, EBLK);
        scan_all<<<1, 1024, 0, stream>>>(ebins, estarts, edeg, estartsN,
                                         adeg, astartsN, NN);
        scatter2<<<EBLK + ABLK, 512, 0, stream>>>(edge_index, edge_attr,
                                                  angle_index, angles, ehs, ahs,
                                                  estarts, ecur, estartsN, ecur50,
                                                  astartsN, acur50,
                                                  se_t, se_src, nidx, sa_t, sa_r,
                                                  E, A, EBLK);
        tilereg_kernel<<<(Tmax + 255) / 256, 256, 0, stream>>>(ebins, estarts, tileReg, Tmax);
        edge_gemm2<<<(Tmax + 3) / 4, 256, 0, stream>>>(xbf, se_t, se_src,
                                                       tileReg, ePQ, mbuf, Tmax, NN);
        reduce_k<<<(NN + 7) / 8, 256, 0, stream>>>(mbuf, nidx, estartsN,
                                                   sa_t, sa_r, astartsN,
                                                   aCD, out, NN);
    } else {
        zero_kernel<<<(out_size / 4 + 255) / 256, 256, 0, stream>>>(out, out_size);
        edge_kernel_fb<<<1024, 256, 0, stream>>>(x, edge_index, edge_attr,
                                                 eW1, eb1, eW2, eb2, out, E);
        angle_kernel_fb<<<1024, 256, 0, stream>>>(angles, angle_index,
                                                  aW1, ab1, aW2, ab2, out, A);
    }
}